// Round 1
// baseline (72.729 us; speedup 1.0000x reference)
//
#include <hip/hip_runtime.h>

// out[b,o] = sum_i amp[o,i] * sin(freq[o,i]*x[b,i] + phase[o,i]) + out_bias[o]
// x: [2048][256] f32, weight: [256][256][2] (amp=..0, freq=..1), bias: [256][257]
// (out_bias = bias[:,0], phase = bias[:,1:]). out: [2048][256] f32.
//
// Strategy: transcendental-bound (134M sines). Use hw v_sin_f32 (input in
// revolutions): pre-scale x by 1/(2pi) at LDS staging, phase by 1/(2pi)
// per-(thread,i) amortized over 4 b's. 256 blocks x 512 threads; block owns
// 8 b-rows x 256 o; thread = (o, b-half), 4 accumulators.

#define INV_2PI 0.15915493667125702f

__global__ __launch_bounds__(512, 2) void ripple_kernel(
    const float* __restrict__ x,
    const float* __restrict__ weight,
    const float* __restrict__ bias,
    float* __restrict__ out)
{
    // transposed x tile: xs[i][b_local]; pad 8->12 so &xs[i][4h] is 16B aligned
    // (row stride 48B) and staging writes are only 2-way bank-conflicted.
    __shared__ float xs[256][12];

    const int tid  = threadIdx.x;
    const int o    = tid & 255;
    const int half = tid >> 8;      // 0..1
    const int b0   = blockIdx.x * 8;

    // stage x (8 rows x 256 cols), transposed + pre-scaled by 1/(2pi)
    {
        float4 v = ((const float4*)(x + b0 * 256))[tid];  // coalesced
        int r = tid >> 6;           // b row 0..7
        int c = (tid & 63) * 4;     // col
        xs[c + 0][r] = v.x * INV_2PI;
        xs[c + 1][r] = v.y * INV_2PI;
        xs[c + 2][r] = v.z * INV_2PI;
        xs[c + 3][r] = v.w * INV_2PI;
    }
    __syncthreads();

    const float4* wq = (const float4*)(weight + o * 512);  // (amp0,f0,amp1,f1) per 2 i
    const float*  pr = bias + o * 257 + 1;                 // phase row
    const float   ob = bias[o * 257];                      // output bias
    const int     bb = half * 4;                           // this thread's 4 b's

    float a0 = 0.f, a1 = 0.f, a2 = 0.f, a3 = 0.f;

    #pragma unroll 8
    for (int i2 = 0; i2 < 128; ++i2) {
        const int i = i2 * 2;
        const float4 w = wq[i2];                 // amp0, freq0, amp1, freq1
        const float p0 = pr[i]     * INV_2PI;
        const float p1 = pr[i + 1] * INV_2PI;
        const float4 xv0 = *(const float4*)&xs[i][bb];      // broadcast, no conflict
        const float4 xv1 = *(const float4*)&xs[i + 1][bb];
        // v_sin_f32 computes sin(2*pi*arg); args pre-scaled to revolutions
        a0 = fmaf(w.x, __builtin_amdgcn_sinf(fmaf(w.y, xv0.x, p0)), a0);
        a1 = fmaf(w.x, __builtin_amdgcn_sinf(fmaf(w.y, xv0.y, p0)), a1);
        a2 = fmaf(w.x, __builtin_amdgcn_sinf(fmaf(w.y, xv0.z, p0)), a2);
        a3 = fmaf(w.x, __builtin_amdgcn_sinf(fmaf(w.y, xv0.w, p0)), a3);
        a0 = fmaf(w.z, __builtin_amdgcn_sinf(fmaf(w.w, xv1.x, p1)), a0);
        a1 = fmaf(w.z, __builtin_amdgcn_sinf(fmaf(w.w, xv1.y, p1)), a1);
        a2 = fmaf(w.z, __builtin_amdgcn_sinf(fmaf(w.w, xv1.z, p1)), a2);
        a3 = fmaf(w.z, __builtin_amdgcn_sinf(fmaf(w.w, xv1.w, p1)), a3);
    }

    float* orow = out + o;
    orow[(b0 + bb + 0) * 256] = a0 + ob;
    orow[(b0 + bb + 1) * 256] = a1 + ob;
    orow[(b0 + bb + 2) * 256] = a2 + ob;
    orow[(b0 + bb + 3) * 256] = a3 + ob;
}

extern "C" void kernel_launch(void* const* d_in, const int* in_sizes, int n_in,
                              void* d_out, int out_size, void* d_ws, size_t ws_size,
                              hipStream_t stream) {
    const float* x      = (const float*)d_in[0];
    const float* weight = (const float*)d_in[1];
    const float* bias   = (const float*)d_in[2];
    float* out          = (float*)d_out;
    // B=2048 -> 256 blocks of 8 b-rows; 512 threads (o x b-half)
    ripple_kernel<<<256, 512, 0, stream>>>(x, weight, bias, out);
}

// Round 2
// 27.996 us; speedup vs baseline: 2.5979x; 2.5979x over previous
//
#include <hip/hip_runtime.h>

// out[b,o] = sum_i amp[o,i]*sin(freq[o,i]*x[b,i] + phase[o,i]) + out_bias[o]
// x:[2048][256] f32, weight:[256][256][2], bias:[256][257]. out:[2048][256].
//
// R2 structure: wave = ONE o (weight/phase loads wave-uniform -> scalar/broadcast,
// 1 cache line per instr instead of 64), lanes = 64 b's. Block = 8 waves = 8 o's
// x 64 b's. Grid = 32 b-blocks x 32 o-blocks = 1024 blocks (8 waves/SIMD max).
// x staged per 32-i chunk in LDS, XOR-swizzled 16B slots so each lane reading
// its own row via ds_read_b128 is bank-conflict-free.
// v_sin_f32 takes revolutions: x pre-scaled at staging, phase scaled with the
// 1/2pi inline constant (free on gfx9).

#define INV_2PI 0.15915493667125702f

__global__ __launch_bounds__(512, 8) void ripple_kernel(
    const float* __restrict__ x,
    const float* __restrict__ weight,
    const float* __restrict__ bias,
    float* __restrict__ out)
{
    __shared__ float xs[64 * 32];   // 8 KB = 512 float4 slots

    const int tid  = threadIdx.x;
    const int lane = tid & 63;
    const int wv   = __builtin_amdgcn_readfirstlane(tid >> 6);  // wave id 0..7
    const int ob   = blockIdx.x & 31;     // o-block
    const int bblk = blockIdx.x >> 5;     // b-block
    const int o    = ob * 8 + wv;         // wave-uniform (SGPR)
    const int b0   = bblk * 64;

    const float* wrow  = weight + o * 512;      // (amp,freq) pairs, uniform addr
    const float* prow  = bias + o * 257 + 1;    // phase row, uniform addr
    const float  obias = bias[o * 257];

    // staging: each thread loads one float4 per chunk
    const int sr    = tid >> 3;                       // row (b) 0..63
    const int sc4   = tid & 7;                        // float4 col 0..7
    const int sslot = sr * 8 + (sc4 ^ (sr & 7));      // XOR-swizzled slot

    float acc0 = 0.f, acc1 = 0.f;

    for (int c = 0; c < 8; ++c) {
        const int i0 = c * 32;
        __syncthreads();
        {
            float4 v = *(const float4*)(x + (b0 + sr) * 256 + i0 + sc4 * 4);
            v.x *= INV_2PI; v.y *= INV_2PI; v.z *= INV_2PI; v.w *= INV_2PI;
            ((float4*)xs)[sslot] = v;
        }
        __syncthreads();

        // this lane's 32 x values (row = lane), swizzled ds_read_b128 x8
        float4 xv[8];
        #pragma unroll
        for (int j = 0; j < 8; ++j)
            xv[j] = ((const float4*)xs)[lane * 8 + (j ^ (lane & 7))];

        #pragma unroll
        for (int j = 0; j < 8; ++j) {
            #pragma unroll
            for (int k = 0; k < 4; ++k) {
                const int i = i0 + j * 4 + k;
                const float am = wrow[2 * i];         // uniform -> SGPR
                const float fr = wrow[2 * i + 1];     // uniform -> SGPR
                const float ph = prow[i] * INV_2PI;   // v_mul s, inline-const
                const float xe = (&xv[j].x)[k];       // static index after unroll
                const float s  = __builtin_amdgcn_sinf(fmaf(fr, xe, ph));
                if (k & 1) acc1 = fmaf(am, s, acc1);
                else       acc0 = fmaf(am, s, acc0);
            }
        }
    }

    const float r = acc0 + acc1 + obias;

    // coalesce the output store through LDS: block result tile is [64 b][8 o]
    __syncthreads();
    xs[wv * 64 + lane] = r;          // xs2[o_local][b_local]
    __syncthreads();
    {
        const int r_ = tid >> 3;     // b_local 0..63
        const int c_ = tid & 7;      // o_local 0..7
        out[(b0 + r_) * 256 + ob * 8 + c_] = xs[c_ * 64 + r_];
    }
}

extern "C" void kernel_launch(void* const* d_in, const int* in_sizes, int n_in,
                              void* d_out, int out_size, void* d_ws, size_t ws_size,
                              hipStream_t stream) {
    const float* x      = (const float*)d_in[0];
    const float* weight = (const float*)d_in[1];
    const float* bias   = (const float*)d_in[2];
    float* out          = (float*)d_out;
    // 32 b-blocks (64 rows each) x 32 o-blocks (8 o each) = 1024 blocks
    ripple_kernel<<<1024, 512, 0, stream>>>(x, weight, bias, out);
}